// Round 9
// baseline (104.439 us; speedup 1.0000x reference)
//
#include <hip/hip_runtime.h>
#include <math.h>

// Problem constants (B=1)
#define T 2048
#define C 1024
#define H 16
#define HD 64
#define N3 (3*C)
#define NBLOCK 2048

typedef __attribute__((ext_vector_type(8))) short bf16x8;
typedef __attribute__((ext_vector_type(4))) float f32x4;

#define MFMA16(a, b, c) __builtin_amdgcn_mfma_f32_16x16x32_bf16((a), (b), (c), 0, 0, 0)

__device__ inline short f2bf(float f) {
    unsigned u; __builtin_memcpy(&u, &f, 4);
    unsigned r = (u + 0x7fffu + ((u >> 16) & 1u)) >> 16;
    return (short)r;
}
__device__ inline float bf2f(short s) {
    unsigned u = ((unsigned)(unsigned short)s) << 16;
    float f; __builtin_memcpy(&f, &u, 4);
    return f;
}

// async global->LDS, 16B per lane. lds base must be wave-uniform; HW adds lane*16.
__device__ inline void gload_lds16(const void* g, void* l) {
    __builtin_amdgcn_global_load_lds((const __attribute__((address_space(1))) unsigned int*)g,
                                     (__attribute__((address_space(3))) unsigned int*)l,
                                     16, 0, 0);
}

// ---------------- merged: conv x + weight transposes + (block 3072) prep + sincos table ----------------
__global__ __launch_bounds__(256) void pre_kernel(const float* __restrict__ x,
                                                  const float* __restrict__ w_attn,
                                                  const float* __restrict__ w_proj,
                                                  const int* __restrict__ tok,
                                                  const float* __restrict__ padmask,
                                                  short* __restrict__ xb,
                                                  short* __restrict__ wabT,
                                                  short* __restrict__ wpbT,
                                                  float2* __restrict__ tab,
                                                  float* __restrict__ pm_tok) {
    int bid = blockIdx.x;
    int tid = threadIdx.x;
    if (bid == 3072) {
        // histogram + scan + pm gather + cos/sin table (single block)
        __shared__ float cntS[NBLOCK];
        __shared__ float sums[256];
        #pragma unroll
        for (int j = 0; j < 8; ++j) cntS[tid * 8 + j] = 0.0f;
        __syncthreads();
        int tk[8];
        #pragma unroll
        for (int j = 0; j < 8; ++j) {
            tk[j] = tok[tid * 8 + j];
            atomicAdd(&cntS[tk[j]], 1.0f);
        }
        __syncthreads();
        float vals[8];
        float s = 0.0f;
        #pragma unroll
        for (int j = 0; j < 8; ++j) {
            s += 1.0f / (cntS[tk[j]] + 1e-10f);
            vals[j] = s;
            pm_tok[tid * 8 + j] = padmask[tk[j]];
        }
        sums[tid] = s;
        __syncthreads();
        for (int off = 1; off < 256; off <<= 1) {
            float v = (tid >= off) ? sums[tid - off] : 0.0f;
            __syncthreads();
            sums[tid] += v;
            __syncthreads();
        }
        float offset = (tid > 0) ? sums[tid - 1] : 0.0f;
        // cos/sin table: thread owns t = tid*8+e, its partial = offset + vals[e]
        float invf[32];
        #pragma unroll
        for (int j = 0; j < 32; ++j)
            invf[j] = exp2f(-(float)j * (13.287712379549449f / 32.0f));  // 10000^(-j/32)
        #pragma unroll
        for (int e = 0; e < 8; ++e) {
            float p = offset + vals[e];
            float2* row = tab + (tid * 8 + e) * 32;
            #pragma unroll
            for (int j = 0; j < 32; ++j) {
                float s_, c_;
                __sincosf(p * invf[j], &s_, &c_);
                row[j] = make_float2(c_, s_);
            }
        }
        return;
    }
    if (bid < 2048) {
        int i = bid * 1024 + tid * 4;
        float4 v = *(const float4*)(x + i);
        short4 o;
        o.x = f2bf(v.x); o.y = f2bf(v.y); o.z = f2bf(v.z); o.w = f2bf(v.w);
        *(short4*)(xb + i) = o;
        return;
    }
    __shared__ float S[64][65];
    const float* in; short* out; int Kd, Nd, bx, by;
    if (bid < 2816) {
        int b = bid - 2048;              // (48, 16)
        bx = b % 48; by = b / 48;
        in = w_attn; out = wabT; Kd = C; Nd = N3;
    } else {
        int b = bid - 2816;              // (16, 16)
        bx = b % 16; by = b / 16;
        in = w_proj; out = wpbT; Kd = C; Nd = C;
    }
    int n0 = bx * 64, k0 = by * 64;
    #pragma unroll
    for (int i = 0; i < 16; ++i) {
        int lin = tid + i * 256;
        int r = lin >> 6, c = lin & 63;
        S[r][c] = in[(size_t)(k0 + r) * Nd + n0 + c];
    }
    __syncthreads();
    #pragma unroll
    for (int i = 0; i < 16; ++i) {
        int lin = tid + i * 256;
        int rn = lin >> 6, ck = lin & 63;
        out[(size_t)(n0 + rn) * Kd + k0 + ck] = f2bf(S[ck][rn]);
    }
}

// ---------------- bf16 GEMM (B^T): 128x(BNF*32) tile, BK=32, 2-phase dbuf ----------------
// EPI=0: plain out (+bias), f32 or bf16 per OUT_BF16.
// EPI=1: fused QKV epilogue — rope(q,k) from tab + d=63 fixups; v scaled+transposed to vbT.
template <int OUT_BF16, int BNF, int EPI>
__global__ __launch_bounds__(256) void gemm_bt(const short* __restrict__ A,
                                               const short* __restrict__ Bt,
                                               const float* __restrict__ bias,
                                               void* __restrict__ Cout,
                                               int M, int N, int K,
                                               const float2* __restrict__ tab,
                                               const float* __restrict__ cumsc,
                                               const float* __restrict__ pm_tok,
                                               short* __restrict__ vbT) {
    constexpr int BN = BNF * 32;
    __shared__ alignas(16) short As[2][128 * 32];
    __shared__ alignas(16) short Bs[2][BN * 32];
    int tid = threadIdx.x;
    int m0 = blockIdx.y * 128, n0 = blockIdx.x * BN;
    int w = tid >> 6, l = tid & 63;
    int wm = (w >> 1) * 64, wn = (w & 1) * (BNF * 16);
    int lq = l & 15, g = l >> 4;
    int prow = l >> 2, pcol = (l & 3) * 8;
    f32x4 acc[4][BNF] = {};

    auto stage = [&](int buf, int k0) {
        #pragma unroll
        for (int i = 0; i < 2; ++i) {
            int c = w * 2 + i;
            int row = c * 16 + prow;
            gload_lds16(A + (size_t)(m0 + row) * K + k0 + pcol, As[buf] + c * 512);
        }
        #pragma unroll
        for (int i = 0; i < BNF / 2; ++i) {
            int c = w * (BNF / 2) + i;
            int row = c * 16 + prow;
            gload_lds16(Bt + (size_t)(n0 + row) * K + k0 + pcol, Bs[buf] + c * 512);
        }
    };

    int NK = K / 32;
    stage(0, 0);
    asm volatile("s_waitcnt vmcnt(0)" ::: "memory");
    __builtin_amdgcn_s_barrier();
    __builtin_amdgcn_sched_barrier(0);

    for (int t = 0; t < NK; ++t) {
        int cur = t & 1;
        if (t + 1 < NK) stage(cur ^ 1, (t + 1) * 32);

        bf16x8 af[4], bfr[BNF];
        #pragma unroll
        for (int f = 0; f < 4; ++f)
            af[f] = *(const bf16x8*)(As[cur] + (wm + f * 16 + lq) * 32 + g * 8);
        #pragma unroll
        for (int j = 0; j < BNF; ++j)
            bfr[j] = *(const bf16x8*)(Bs[cur] + (wn + j * 16 + lq) * 32 + g * 8);
        __builtin_amdgcn_s_setprio(1);
        #pragma unroll
        for (int fi = 0; fi < 4; ++fi)
            #pragma unroll
            for (int fj = 0; fj < BNF; ++fj)
                acc[fi][fj] = MFMA16(af[fi], bfr[fj], acc[fi][fj]);
        __builtin_amdgcn_s_setprio(0);

        asm volatile("s_waitcnt vmcnt(0)" ::: "memory");
        __builtin_amdgcn_s_barrier();
        __builtin_amdgcn_sched_barrier(0);
    }

    if (EPI == 0) {
        #pragma unroll
        for (int fi = 0; fi < 4; ++fi)
            #pragma unroll
            for (int fj = 0; fj < BNF; ++fj)
                #pragma unroll
                for (int r = 0; r < 4; ++r) {
                    int m = m0 + wm + fi * 16 + g * 4 + r;
                    int n = n0 + wn + fj * 16 + lq;
                    float v = acc[fi][fj][r] + bias[n];
                    if (OUT_BF16) ((short*)Cout)[(size_t)m * N + n] = f2bf(v);
                    else          ((float*)Cout)[(size_t)m * N + n] = v;
                }
    } else {
        // BNF == 4: wave strip is exactly one head (64 cols) at n0+wn.
        short* Cb = (short*)Cout;              // qkvb
        int section = n0 >> 10;                // 0 q, 1 k, 2 v
        int cb = n0 + wn;                      // wave's absolute col base
        float b0 = bias[cb + lq],      b1 = bias[cb + 16 + lq];
        float b2 = bias[cb + 32 + lq], b3 = bias[cb + 48 + lq];
        if (section < 2) {
            bool isQ = (section == 0);
            #pragma unroll
            for (int fi = 0; fi < 4; ++fi)
                #pragma unroll
                for (int r = 0; r < 4; ++r) {
                    int trow = m0 + wm + fi * 16 + g * 4 + r;
                    float pm = pm_tok[trow];
                    float csc = cumsc[trow];
                    float2 cs0 = tab[trow * 32 + lq];
                    float2 cs1 = tab[trow * 32 + 16 + lq];
                    float a0 = acc[fi][0][r] + b0;
                    float a1 = acc[fi][1][r] + b1;
                    float a2 = acc[fi][2][r] + b2;
                    float a3 = acc[fi][3][r] + b3;
                    float lo0 = a0 * cs0.x - a2 * cs0.y;
                    float hi0 = a2 * cs0.x + a0 * cs0.y;
                    float lo1 = a1 * cs1.x - a3 * cs1.y;
                    float hi1 = a3 * cs1.x + a1 * cs1.y;
                    if (lq == 15)   // d == 63 fixups (padding folded in)
                        hi1 = isQ ? ((pm != 0.0f) ? 1.0f : 0.0f)
                                  : ((pm != 0.0f) ? csc : -1e20f);
                    size_t base = (size_t)trow * N3 + cb;
                    Cb[base + lq]      = f2bf(lo0);
                    Cb[base + 16 + lq] = f2bf(lo1);
                    Cb[base + 32 + lq] = f2bf(hi0);
                    Cb[base + 48 + lq] = f2bf(hi1);
                }
        } else {
            // V: write only transposed + exp(cum)-scaled vbT[h*64+d][t], 8B stores (4 consecutive t)
            int h = (cb - 2 * C) >> 6;
            #pragma unroll
            for (int fi = 0; fi < 4; ++fi) {
                int tb = m0 + wm + fi * 16 + g * 4;
                float ef[4];
                #pragma unroll
                for (int r = 0; r < 4; ++r) ef[r] = __expf(cumsc[tb + r]);
                #pragma unroll
                for (int fj = 0; fj < 4; ++fj) {
                    int d = fj * 16 + lq;
                    float bv = bias[cb + fj * 16 + lq];
                    short4 o;
                    o.x = f2bf((acc[fi][fj][0] + bv) * ef[0]);
                    o.y = f2bf((acc[fi][fj][1] + bv) * ef[1]);
                    o.z = f2bf((acc[fi][fj][2] + bv) * ef[2]);
                    o.w = f2bf((acc[fi][fj][3] + bv) * ef[3]);
                    *(short4*)(vbT + (size_t)(h * 64 + d) * T + tb) = o;
                }
            }
        }
    }
}

// ---------------- MFMA flash attention: staged dbuf + streaming softmax + paired balance ----------------
// 512 blocks. Pair (b, b+256) -> same XCD (256%8==0): work sums to 33 tiles.
__global__ __launch_bounds__(256) void attn_flash(const short* __restrict__ qkvb,
                                                  const short* __restrict__ vbT,
                                                  short* __restrict__ yb) {
    __shared__ alignas(16) short Kt[2][64 * 64];      // [k][d], XOR-swizzled rows
    __shared__ alignas(16) short Vt[2][64 * 64];      // [d][k], XOR-swizzled rows
    __shared__ alignas(16) short Ps[4][16][72];       // wave-private P[q][k]

    int b = blockIdx.x;
    int h, qt;
    if (b < 256) { h = b & 15; qt = 31 - (b >> 4); }
    else         { int c2 = b - 256; h = c2 & 15; qt = c2 >> 4; }
    int tid = threadIdx.x;
    int w = tid >> 6, l = tid & 63;
    int lq = l & 15, g = l >> 4;
    int qrl = w * 16 + lq;

    const short* qbase = qkvb + (size_t)(qt * 64 + qrl) * N3 + h * 64;
    bf16x8 qf0 = *(const bf16x8*)(qbase + g * 8);
    bf16x8 qf1 = *(const bf16x8*)(qbase + 32 + g * 8);

    f32x4 accO[4] = {};
    float lsum = 0.0f;

    int srow = tid >> 3, scol = (tid & 7) * 8;
    const short* kgb = qkvb + C + h * 64 + scol;
    const short* vgb = vbT + (size_t)(h * 64) * T + scol;
    int wb0 = srow * 128 + ((scol * 2) ^ ((srow & 7) << 4));
    int wb1 = (srow + 32) * 128 + ((scol * 2) ^ ((srow & 7) << 4));

    auto do_tile = [&](int cur, bool masked) {
        const char* Kc = (const char*)Kt[cur];
        const char* Vc = (const char*)Vt[cur];
        f32x4 s[4] = {};
        __builtin_amdgcn_s_setprio(1);
        #pragma unroll
        for (int f = 0; f < 4; ++f) {
            int row = f * 16 + lq;
            const char* kr_ = Kc + row * 128;
            int sw = (row & 7) << 4;
            bf16x8 a0 = *(const bf16x8*)(kr_ + ((g * 16) ^ sw));
            bf16x8 a1 = *(const bf16x8*)(kr_ + ((64 + g * 16) ^ sw));
            s[f] = MFMA16(a0, qf0, s[f]);
            s[f] = MFMA16(a1, qf1, s[f]);
        }
        __builtin_amdgcn_s_setprio(0);
        float p[16];
        #pragma unroll
        for (int f = 0; f < 4; ++f)
            #pragma unroll
            for (int r = 0; r < 4; ++r) {
                float sv = s[f][r] * 0.125f;
                if (masked) {
                    int kl = f * 16 + g * 4 + r;
                    sv = (kl > qrl) ? -INFINITY : sv;
                }
                float pv = __expf(sv);
                p[f * 4 + r] = pv;
                lsum += pv;
            }
        #pragma unroll
        for (int f = 0; f < 4; ++f) {
            unsigned u0, u1;
            asm("v_cvt_pk_bf16_f32 %0, %1, %2" : "=v"(u0) : "v"(p[f * 4 + 0]), "v"(p[f * 4 + 1]));
            asm("v_cvt_pk_bf16_f32 %0, %1, %2" : "=v"(u1) : "v"(p[f * 4 + 2]), "v"(p[f * 4 + 3]));
            uint2 uu; uu.x = u0; uu.y = u1;
            *(uint2*)&Ps[w][lq][f * 16 + g * 4] = uu;
        }
        __builtin_amdgcn_s_setprio(1);
        #pragma unroll
        for (int kh = 0; kh < 2; ++kh) {
            bf16x8 pa = *(const bf16x8*)&Ps[w][lq][kh * 32 + g * 8];
            #pragma unroll
            for (int f = 0; f < 4; ++f) {
                int vrow = f * 16 + lq;
                const char* vr_ = Vc + vrow * 128;
                bf16x8 vb = *(const bf16x8*)(vr_ + (((kh * 32 + g * 8) * 2) ^ ((vrow & 7) << 4)));
                accO[f] = MFMA16(pa, vb, accO[f]);
            }
        }
        __builtin_amdgcn_s_setprio(0);
    };

    uint4 kr0 = *(const uint4*)(kgb + (size_t)srow * N3);
    uint4 kr1 = *(const uint4*)(kgb + (size_t)(srow + 32) * N3);
    uint4 vr0 = *(const uint4*)(vgb + (size_t)srow * T);
    uint4 vr1 = *(const uint4*)(vgb + (size_t)(srow + 32) * T);
    *(uint4*)((char*)Kt[0] + wb0) = kr0;
    *(uint4*)((char*)Kt[0] + wb1) = kr1;
    *(uint4*)((char*)Vt[0] + wb0) = vr0;
    *(uint4*)((char*)Vt[0] + wb1) = vr1;
    __syncthreads();

    for (int t = 0; t < qt; ++t) {
        int kn = (t + 1) * 64;
        kr0 = *(const uint4*)(kgb + (size_t)(kn + srow) * N3);
        kr1 = *(const uint4*)(kgb + (size_t)(kn + srow + 32) * N3);
        vr0 = *(const uint4*)(vgb + (size_t)srow * T + kn);
        vr1 = *(const uint4*)(vgb + (size_t)(srow + 32) * T + kn);

        do_tile(t & 1, false);

        int nxt = (t & 1) ^ 1;
        *(uint4*)((char*)Kt[nxt] + wb0) = kr0;
        *(uint4*)((char*)Kt[nxt] + wb1) = kr1;
        *(uint4*)((char*)Vt[nxt] + wb0) = vr0;
        *(uint4*)((char*)Vt[nxt] + wb1) = vr1;
        __syncthreads();
    }
    do_tile(qt & 1, true);

    lsum += __shfl_xor(lsum, 16);
    lsum += __shfl_xor(lsum, 32);
    float linv_own = 1.0f / lsum;
    float li[4];
    #pragma unroll
    for (int r = 0; r < 4; ++r) li[r] = __shfl(linv_own, g * 4 + r);

    #pragma unroll
    for (int f = 0; f < 4; ++f)
        #pragma unroll
        for (int r = 0; r < 4; ++r) {
            int trow = qt * 64 + w * 16 + g * 4 + r;
            yb[(size_t)trow * C + h * 64 + f * 16 + lq] = f2bf(accO[f][r] * li[r]);
        }
}

extern "C" void kernel_launch(void* const* d_in, const int* in_sizes, int n_in,
                              void* d_out, int out_size, void* d_ws, size_t ws_size,
                              hipStream_t stream) {
    const float* x       = (const float*)d_in[0];
    const float* cumsc   = (const float*)d_in[1];
    const float* padmask = (const float*)d_in[2];
    const int*   tok     = (const int*)d_in[3];
    const float* w_attn  = (const float*)d_in[4];
    const float* b_attn  = (const float*)d_in[5];
    const float* w_proj  = (const float*)d_in[6];
    const float* b_proj  = (const float*)d_in[7];
    float* out = (float*)d_out;

    float*  pm_tok = (float*)d_ws;                     // 2048
    float2* tab    = (float2*)(pm_tok + 2048);         // 2048*32 float2 (512KB)
    short*  xb     = (short*)(pm_tok + 2048 + 131072); // T*C
    short*  wabT   = xb + (size_t)T * C;               // 3C*C
    short*  wpbT   = wabT + (size_t)N3 * C;            // C*C
    short*  qkvb   = wpbT + (size_t)C * C;             // T*3C (v-section unused)
    short*  vbT    = qkvb + (size_t)T * N3;            // C*T
    short*  yb     = vbT + (size_t)C * T;              // T*C

    pre_kernel<<<3073, 256, 0, stream>>>(x, w_attn, w_proj, tok, padmask,
                                         xb, wabT, wpbT, tab, pm_tok);
    gemm_bt<1, 4, 1><<<dim3(N3 / 128, T / 128), 256, 0, stream>>>(
        xb, wabT, b_attn, qkvb, T, N3, C, tab, cumsc, pm_tok, vbT);
    attn_flash<<<512, 256, 0, stream>>>(qkvb, vbT, yb);
    gemm_bt<0, 2, 0><<<dim3(C / 64, T / 128), 256, 0, stream>>>(
        yb, wpbT, b_proj, out, T, C, C, nullptr, nullptr, nullptr, nullptr);
}

// Round 10
// 92.195 us; speedup vs baseline: 1.1328x; 1.1328x over previous
//
#include <hip/hip_runtime.h>
#include <math.h>

// Problem constants (B=1)
#define T 2048
#define C 1024
#define H 16
#define HD 64
#define N3 (3*C)
#define NBLOCK 2048

typedef __attribute__((ext_vector_type(8))) short bf16x8;
typedef __attribute__((ext_vector_type(4))) float f32x4;

#define MFMA16(a, b, c) __builtin_amdgcn_mfma_f32_16x16x32_bf16((a), (b), (c), 0, 0, 0)

__device__ inline short f2bf(float f) {
    unsigned u; __builtin_memcpy(&u, &f, 4);
    unsigned r = (u + 0x7fffu + ((u >> 16) & 1u)) >> 16;
    return (short)r;
}
__device__ inline float bf2f(short s) {
    unsigned u = ((unsigned)(unsigned short)s) << 16;
    float f; __builtin_memcpy(&f, &u, 4);
    return f;
}

// async global->LDS, 16B per lane. lds base must be wave-uniform; HW adds lane*16.
__device__ inline void gload_lds16(const void* g, void* l) {
    __builtin_amdgcn_global_load_lds((const __attribute__((address_space(1))) unsigned int*)g,
                                     (__attribute__((address_space(3))) unsigned int*)l,
                                     16, 0, 0);
}

// ---------------- merged: conv x + weight transposes + (block 3072) hist/scan prep ----------------
__global__ __launch_bounds__(256) void pre_kernel(const float* __restrict__ x,
                                                  const float* __restrict__ w_attn,
                                                  const float* __restrict__ w_proj,
                                                  const int* __restrict__ tok,
                                                  const float* __restrict__ padmask,
                                                  short* __restrict__ xb,
                                                  short* __restrict__ wabT,
                                                  short* __restrict__ wpbT,
                                                  float* __restrict__ partial,
                                                  float* __restrict__ pm_tok) {
    int bid = blockIdx.x;
    int tid = threadIdx.x;
    if (bid == 3072) {
        // fused histogram + scan + pm gather (single block)
        __shared__ float cntS[NBLOCK];
        __shared__ float sums[256];
        #pragma unroll
        for (int j = 0; j < 8; ++j) cntS[tid * 8 + j] = 0.0f;
        __syncthreads();
        int tk[8];
        #pragma unroll
        for (int j = 0; j < 8; ++j) {
            tk[j] = tok[tid * 8 + j];
            atomicAdd(&cntS[tk[j]], 1.0f);
        }
        __syncthreads();
        float vals[8];
        float s = 0.0f;
        #pragma unroll
        for (int j = 0; j < 8; ++j) {
            s += 1.0f / (cntS[tk[j]] + 1e-10f);
            vals[j] = s;
            pm_tok[tid * 8 + j] = padmask[tk[j]];
        }
        sums[tid] = s;
        __syncthreads();
        for (int off = 1; off < 256; off <<= 1) {
            float v = (tid >= off) ? sums[tid - off] : 0.0f;
            __syncthreads();
            sums[tid] += v;
            __syncthreads();
        }
        float offset = (tid > 0) ? sums[tid - 1] : 0.0f;
        #pragma unroll
        for (int j = 0; j < 8; ++j) partial[tid * 8 + j] = offset + vals[j];
        return;
    }
    if (bid < 2048) {
        int i = bid * 1024 + tid * 4;
        float4 v = *(const float4*)(x + i);
        short4 o;
        o.x = f2bf(v.x); o.y = f2bf(v.y); o.z = f2bf(v.z); o.w = f2bf(v.w);
        *(short4*)(xb + i) = o;
        return;
    }
    __shared__ float S[64][65];
    const float* in; short* out; int Kd, Nd, bx, by;
    if (bid < 2816) {
        int b = bid - 2048;              // (48, 16)
        bx = b % 48; by = b / 48;
        in = w_attn; out = wabT; Kd = C; Nd = N3;
    } else {
        int b = bid - 2816;              // (16, 16)
        bx = b % 16; by = b / 16;
        in = w_proj; out = wpbT; Kd = C; Nd = C;
    }
    int n0 = bx * 64, k0 = by * 64;
    #pragma unroll
    for (int i = 0; i < 16; ++i) {
        int lin = tid + i * 256;
        int r = lin >> 6, c = lin & 63;
        S[r][c] = in[(size_t)(k0 + r) * Nd + n0 + c];
    }
    __syncthreads();
    #pragma unroll
    for (int i = 0; i < 16; ++i) {
        int lin = tid + i * 256;
        int rn = lin >> 6, ck = lin & 63;
        out[(size_t)(n0 + rn) * Kd + k0 + ck] = f2bf(S[ck][rn]);
    }
}

// ---------------- bf16 GEMM (B^T): 64x128 tile, BK=32, 4 waves (2x2) ----------------
// Grid (N/128, M/64): QKV -> 768 blocks (3/CU uniform), proj -> 256 (1/CU uniform).
// acc[2][4] = 32 VGPR/wave; 12KB LDS -> ~8 resident blocks/CU for latency hiding.
template <int OUT_BF16>
__global__ __launch_bounds__(256) void gemm_bt64(const short* __restrict__ A,
                                                 const short* __restrict__ Bt,
                                                 const float* __restrict__ bias,
                                                 void* __restrict__ Cout,
                                                 int M, int N, int K) {
    __shared__ alignas(16) short As[64 * 32];
    __shared__ alignas(16) short Bs[128 * 32];
    int tid = threadIdx.x;
    int m0 = blockIdx.y * 64, n0 = blockIdx.x * 128;
    int w = tid >> 6, l = tid & 63;
    int wm = (w >> 1) * 32, wn = (w & 1) * 64;
    int lq = l & 15, g = l >> 4;
    int prow = l >> 2, pcol = (l & 3) * 8;    // lane slot within a 1KB chunk (16 rows x 32 cols)
    f32x4 acc[2][4] = {};
    for (int k0 = 0; k0 < K; k0 += 32) {
        {   // A: 4 chunks (1 per wave); B: 8 chunks (2 per wave)
            int rowA = w * 16 + prow;
            gload_lds16(A + (size_t)(m0 + rowA) * K + k0 + pcol, As + w * 512);
            #pragma unroll
            for (int i = 0; i < 2; ++i) {
                int c = w * 2 + i;
                int row = c * 16 + prow;
                gload_lds16(Bt + (size_t)(n0 + row) * K + k0 + pcol, Bs + c * 512);
            }
        }
        __syncthreads();
        bf16x8 af[2], bfr[4];
        #pragma unroll
        for (int f = 0; f < 2; ++f)
            af[f] = *(const bf16x8*)(As + (wm + f * 16 + lq) * 32 + g * 8);
        #pragma unroll
        for (int j = 0; j < 4; ++j)
            bfr[j] = *(const bf16x8*)(Bs + (wn + j * 16 + lq) * 32 + g * 8);
        #pragma unroll
        for (int fi = 0; fi < 2; ++fi)
            #pragma unroll
            for (int fj = 0; fj < 4; ++fj)
                acc[fi][fj] = MFMA16(af[fi], bfr[fj], acc[fi][fj]);
        __syncthreads();
    }
    #pragma unroll
    for (int fi = 0; fi < 2; ++fi)
        #pragma unroll
        for (int fj = 0; fj < 4; ++fj)
            #pragma unroll
            for (int r = 0; r < 4; ++r) {
                int m = m0 + wm + fi * 16 + g * 4 + r;
                int n = n0 + wn + fj * 16 + lq;
                float v = acc[fi][fj][r] + bias[n];
                if (OUT_BF16) ((short*)Cout)[(size_t)m * N + n] = f2bf(v);
                else          ((float*)Cout)[(size_t)m * N + n] = v;
            }
}

// ---------------- merged RoPE(q,k) + V transpose/scale ----------------
__global__ __launch_bounds__(256) void ropevt(short* __restrict__ qkvb,
                                              const float* __restrict__ partial,
                                              const float* __restrict__ cumsc,
                                              const float* __restrict__ pm_tok,
                                              short* __restrict__ vbT) {
    __shared__ alignas(16) short S[64][72];
    __shared__ float efs[64];
    int bid = blockIdx.x;
    int tid = threadIdx.x;
    if (bid < 512) {
        // RoPE: 4 tokens per block, shfl-shared sincos; padding folded into d=63 fixups
        int tg = tid >> 6, l = tid & 63;
        int t = bid * 4 + tg;
        int j = l & 31;
        float inv = exp2f(-(float)j * (13.287712379549449f / 32.0f));  // 10000^(-j/32)
        float ang = partial[t] * inv;
        float cs_own = cosf(ang), sn_own = sinf(ang);
        float csc = cumsc[t];
        float pmv = pm_tok[t];
        float qfix = (pmv != 0.0f) ? 1.0f : 0.0f;
        float kfix = (pmv != 0.0f) ? csc : -1e20f;

        int h = l >> 2, jb = (l & 3) * 8;
        short* row = qkvb + (size_t)t * N3;
        int c1 = h * 64 + jb;
        bf16x8 qlo = *(const bf16x8*)(row + c1);
        bf16x8 qhi = *(const bf16x8*)(row + c1 + 32);
        bf16x8 klo = *(const bf16x8*)(row + C + c1);
        bf16x8 khi = *(const bf16x8*)(row + C + c1 + 32);
        bf16x8 qlo2, qhi2, klo2, khi2;
        #pragma unroll
        for (int i = 0; i < 8; ++i) {
            float cs = __shfl(cs_own, jb + i);
            float sn = __shfl(sn_own, jb + i);
            float q1 = bf2f(qlo[i]), q2 = bf2f(qhi[i]);
            float k1 = bf2f(klo[i]), k2 = bf2f(khi[i]);
            float q2n = q2 * cs + q1 * sn;
            float k2n = k2 * cs + k1 * sn;
            if (jb + i == 31) { q2n = qfix; k2n = kfix; }
            qlo2[i] = f2bf(q1 * cs - q2 * sn);
            qhi2[i] = f2bf(q2n);
            klo2[i] = f2bf(k1 * cs - k2 * sn);
            khi2[i] = f2bf(k2n);
        }
        *(bf16x8*)(row + c1) = qlo2;
        *(bf16x8*)(row + c1 + 32) = qhi2;
        *(bf16x8*)(row + C + c1) = klo2;
        *(bf16x8*)(row + C + c1 + 32) = khi2;
        return;
    }
    // V transpose + exp(cum) scale
    int b = bid - 512;
    int h = b >> 5;
    int t0 = (b & 31) * 64;
    if (tid < 64) efs[tid] = __expf(cumsc[t0 + tid]);
    __syncthreads();
    #pragma unroll
    for (int e = 0; e < 2; ++e) {
        int s = tid * 2 + e;
        int r = s >> 3, c8 = (s & 7) * 8;
        bf16x8 v = *(const bf16x8*)(qkvb + (size_t)(t0 + r) * N3 + 2 * C + h * 64 + c8);
        float ef = efs[r];
        bf16x8 o;
        #pragma unroll
        for (int i = 0; i < 8; ++i) o[i] = f2bf(bf2f(v[i]) * ef);
        *(bf16x8*)&S[r][c8] = o;
    }
    __syncthreads();
    #pragma unroll
    for (int e = 0; e < 2; ++e) {
        int s = tid * 2 + e;
        int d = s >> 3, t8 = (s & 7) * 8;
        bf16x8 o;
        #pragma unroll
        for (int i = 0; i < 8; ++i) o[i] = S[t8 + i][d];
        *(bf16x8*)(vbT + (size_t)(h * 64 + d) * T + t0 + t8) = o;
    }
}

// ---------------- MFMA flash attention: staged dbuf + streaming softmax + paired balance ----------------
// 512 blocks. Pair (b, b+256) -> same XCD (256%8==0): work sums to 33 tiles.
__global__ __launch_bounds__(256) void attn_flash(const short* __restrict__ qkvb,
                                                  const short* __restrict__ vbT,
                                                  short* __restrict__ yb) {
    __shared__ alignas(16) short Kt[2][64 * 64];      // [k][d], XOR-swizzled rows
    __shared__ alignas(16) short Vt[2][64 * 64];      // [d][k], XOR-swizzled rows
    __shared__ alignas(16) short Ps[4][16][72];       // wave-private P[q][k]

    int b = blockIdx.x;
    int h, qt;
    if (b < 256) { h = b & 15; qt = 31 - (b >> 4); }          // long half: qt 16..31
    else         { int c2 = b - 256; h = c2 & 15; qt = c2 >> 4; }  // short half: qt 0..15
    int tid = threadIdx.x;
    int w = tid >> 6, l = tid & 63;
    int lq = l & 15, g = l >> 4;
    int qrl = w * 16 + lq;                             // q-row local to the 64-row q-tile

    const short* qbase = qkvb + (size_t)(qt * 64 + qrl) * N3 + h * 64;
    bf16x8 qf0 = *(const bf16x8*)(qbase + g * 8);
    bf16x8 qf1 = *(const bf16x8*)(qbase + 32 + g * 8);

    f32x4 accO[4] = {};    // [f]: d = 16f + lq ; q-rows = 4g + r
    float lsum = 0.0f;

    // staging geometry: thread covers rows srow, srow+32; 8 cols at scol
    int srow = tid >> 3, scol = (tid & 7) * 8;
    const short* kgb = qkvb + C + h * 64 + scol;
    const short* vgb = vbT + (size_t)(h * 64) * T + scol;
    int wb0 = srow * 128 + ((scol * 2) ^ ((srow & 7) << 4));
    int wb1 = (srow + 32) * 128 + ((scol * 2) ^ ((srow & 7) << 4));

    auto do_tile = [&](int cur, bool masked) {
        const char* Kc = (const char*)Kt[cur];
        const char* Vc = (const char*)Vt[cur];
        // ---- S^T = K · Q^T ----
        f32x4 s[4] = {};
        __builtin_amdgcn_s_setprio(1);
        #pragma unroll
        for (int f = 0; f < 4; ++f) {
            int row = f * 16 + lq;
            const char* kr_ = Kc + row * 128;
            int sw = (row & 7) << 4;
            bf16x8 a0 = *(const bf16x8*)(kr_ + ((g * 16) ^ sw));
            bf16x8 a1 = *(const bf16x8*)(kr_ + ((64 + g * 16) ^ sw));
            s[f] = MFMA16(a0, qf0, s[f]);
            s[f] = MFMA16(a1, qf1, s[f]);
        }
        __builtin_amdgcn_s_setprio(0);
        // ---- streaming softmax: p = exp(s/8), no max-tracking ----
        float p[16];
        #pragma unroll
        for (int f = 0; f < 4; ++f)
            #pragma unroll
            for (int r = 0; r < 4; ++r) {
                float sv = s[f][r] * 0.125f;
                if (masked) {
                    int kl = f * 16 + g * 4 + r;
                    sv = (kl > qrl) ? -INFINITY : sv;
                }
                float pv = __expf(sv);
                p[f * 4 + r] = pv;
                lsum += pv;
            }
        // ---- pack P to bf16, transpose through wave-private LDS ----
        #pragma unroll
        for (int f = 0; f < 4; ++f) {
            unsigned u0, u1;
            asm("v_cvt_pk_bf16_f32 %0, %1, %2" : "=v"(u0) : "v"(p[f * 4 + 0]), "v"(p[f * 4 + 1]));
            asm("v_cvt_pk_bf16_f32 %0, %1, %2" : "=v"(u1) : "v"(p[f * 4 + 2]), "v"(p[f * 4 + 3]));
            uint2 uu; uu.x = u0; uu.y = u1;
            *(uint2*)&Ps[w][lq][f * 16 + g * 4] = uu;
        }
        // ---- O += P · V ----
        __builtin_amdgcn_s_setprio(1);
        #pragma unroll
        for (int kh = 0; kh < 2; ++kh) {
            bf16x8 pa = *(const bf16x8*)&Ps[w][lq][kh * 32 + g * 8];
            #pragma unroll
            for (int f = 0; f < 4; ++f) {
                int vrow = f * 16 + lq;
                const char* vr_ = Vc + vrow * 128;
                bf16x8 vb = *(const bf16x8*)(vr_ + (((kh * 32 + g * 8) * 2) ^ ((vrow & 7) << 4)));
                accO[f] = MFMA16(pa, vb, accO[f]);
            }
        }
        __builtin_amdgcn_s_setprio(0);
    };

    // prologue: stage tile 0
    uint4 kr0 = *(const uint4*)(kgb + (size_t)srow * N3);
    uint4 kr1 = *(const uint4*)(kgb + (size_t)(srow + 32) * N3);
    uint4 vr0 = *(const uint4*)(vgb + (size_t)srow * T);
    uint4 vr1 = *(const uint4*)(vgb + (size_t)(srow + 32) * T);
    *(uint4*)((char*)Kt[0] + wb0) = kr0;
    *(uint4*)((char*)Kt[0] + wb1) = kr1;
    *(uint4*)((char*)Vt[0] + wb0) = vr0;
    *(uint4*)((char*)Vt[0] + wb1) = vr1;
    __syncthreads();

    for (int t = 0; t < qt; ++t) {
        int kn = (t + 1) * 64;
        kr0 = *(const uint4*)(kgb + (size_t)(kn + srow) * N3);
        kr1 = *(const uint4*)(kgb + (size_t)(kn + srow + 32) * N3);
        vr0 = *(const uint4*)(vgb + (size_t)srow * T + kn);
        vr1 = *(const uint4*)(vgb + (size_t)(srow + 32) * T + kn);

        do_tile(t & 1, false);

        int nxt = (t & 1) ^ 1;
        *(uint4*)((char*)Kt[nxt] + wb0) = kr0;
        *(uint4*)((char*)Kt[nxt] + wb1) = kr1;
        *(uint4*)((char*)Vt[nxt] + wb0) = vr0;
        *(uint4*)((char*)Vt[nxt] + wb1) = vr1;
        __syncthreads();
    }
    do_tile(qt & 1, true);   // diagonal tile, causal mask

    // final l reduction over the 4 g-groups
    lsum += __shfl_xor(lsum, 16);
    lsum += __shfl_xor(lsum, 32);
    float linv_own = 1.0f / lsum;
    float li[4];
    #pragma unroll
    for (int r = 0; r < 4; ++r) li[r] = __shfl(linv_own, g * 4 + r);

    #pragma unroll
    for (int f = 0; f < 4; ++f)
        #pragma unroll
        for (int r = 0; r < 4; ++r) {
            int trow = qt * 64 + w * 16 + g * 4 + r;
            yb[(size_t)trow * C + h * 64 + f * 16 + lq] = f2bf(accO[f][r] * li[r]);
        }
}

extern "C" void kernel_launch(void* const* d_in, const int* in_sizes, int n_in,
                              void* d_out, int out_size, void* d_ws, size_t ws_size,
                              hipStream_t stream) {
    const float* x       = (const float*)d_in[0];
    const float* cumsc   = (const float*)d_in[1];
    const float* padmask = (const float*)d_in[2];
    const int*   tok     = (const int*)d_in[3];
    const float* w_attn  = (const float*)d_in[4];
    const float* b_attn  = (const float*)d_in[5];
    const float* w_proj  = (const float*)d_in[6];
    const float* b_proj  = (const float*)d_in[7];
    float* out = (float*)d_out;

    float* part   = (float*)d_ws;                 // 2048
    float* pm_tok = part + 2048;                  // 2048
    short* xb     = (short*)(pm_tok + 2048);      // T*C
    short* wabT   = xb + (size_t)T * C;           // 3C*C
    short* wpbT   = wabT + (size_t)N3 * C;        // C*C
    short* qkvb   = wpbT + (size_t)C * C;         // T*3C
    short* vbT    = qkvb + (size_t)T * N3;        // C*T
    short* yb     = vbT + (size_t)C * T;          // T*C

    pre_kernel<<<3073, 256, 0, stream>>>(x, w_attn, w_proj, tok, padmask,
                                         xb, wabT, wpbT, part, pm_tok);
    gemm_bt64<1><<<dim3(N3 / 128, T / 64), 256, 0, stream>>>(xb, wabT, b_attn, qkvb, T, N3, C);
    ropevt<<<1024, 256, 0, stream>>>(qkvb, part, cumsc, pm_tok, vbT);
    attn_flash<<<512, 256, 0, stream>>>(qkvb, vbT, yb);
    gemm_bt64<0><<<dim3(C / 128, T / 64), 256, 0, stream>>>(yb, wpbT, b_proj, out, T, C, C);
}

// Round 11
// 88.533 us; speedup vs baseline: 1.1797x; 1.0414x over previous
//
#include <hip/hip_runtime.h>
#include <math.h>

// Problem constants (B=1)
#define T 2048
#define C 1024
#define H 16
#define HD 64
#define N3 (3*C)
#define NBLOCK 2048

typedef __attribute__((ext_vector_type(8))) short bf16x8;
typedef __attribute__((ext_vector_type(4))) float f32x4;

#define MFMA16(a, b, c) __builtin_amdgcn_mfma_f32_16x16x32_bf16((a), (b), (c), 0, 0, 0)

__device__ inline short f2bf(float f) {
    unsigned u; __builtin_memcpy(&u, &f, 4);
    unsigned r = (u + 0x7fffu + ((u >> 16) & 1u)) >> 16;
    return (short)r;
}
__device__ inline float bf2f(short s) {
    unsigned u = ((unsigned)(unsigned short)s) << 16;
    float f; __builtin_memcpy(&f, &u, 4);
    return f;
}

// async global->LDS, 16B per lane. lds base must be wave-uniform; HW adds lane*16.
__device__ inline void gload_lds16(const void* g, void* l) {
    __builtin_amdgcn_global_load_lds((const __attribute__((address_space(1))) unsigned int*)g,
                                     (__attribute__((address_space(3))) unsigned int*)l,
                                     16, 0, 0);
}

// ---------------- merged: conv x + weight transposes + (block 3072) hist/scan prep ----------------
__global__ __launch_bounds__(256) void pre_kernel(const float* __restrict__ x,
                                                  const float* __restrict__ w_attn,
                                                  const float* __restrict__ w_proj,
                                                  const int* __restrict__ tok,
                                                  const float* __restrict__ padmask,
                                                  short* __restrict__ xb,
                                                  short* __restrict__ wabT,
                                                  short* __restrict__ wpbT,
                                                  float* __restrict__ partial,
                                                  float* __restrict__ pm_tok) {
    int bid = blockIdx.x;
    int tid = threadIdx.x;
    if (bid == 3072) {
        // fused histogram + scan + pm gather (single block)
        __shared__ float cntS[NBLOCK];
        __shared__ float sums[256];
        #pragma unroll
        for (int j = 0; j < 8; ++j) cntS[tid * 8 + j] = 0.0f;
        __syncthreads();
        int tk[8];
        #pragma unroll
        for (int j = 0; j < 8; ++j) {
            tk[j] = tok[tid * 8 + j];
            atomicAdd(&cntS[tk[j]], 1.0f);
        }
        __syncthreads();
        float vals[8];
        float s = 0.0f;
        #pragma unroll
        for (int j = 0; j < 8; ++j) {
            s += 1.0f / (cntS[tk[j]] + 1e-10f);
            vals[j] = s;
            pm_tok[tid * 8 + j] = padmask[tk[j]];
        }
        sums[tid] = s;
        __syncthreads();
        for (int off = 1; off < 256; off <<= 1) {
            float v = (tid >= off) ? sums[tid - off] : 0.0f;
            __syncthreads();
            sums[tid] += v;
            __syncthreads();
        }
        float offset = (tid > 0) ? sums[tid - 1] : 0.0f;
        #pragma unroll
        for (int j = 0; j < 8; ++j) partial[tid * 8 + j] = offset + vals[j];
        return;
    }
    if (bid < 2048) {
        int i = bid * 1024 + tid * 4;
        float4 v = *(const float4*)(x + i);
        short4 o;
        o.x = f2bf(v.x); o.y = f2bf(v.y); o.z = f2bf(v.z); o.w = f2bf(v.w);
        *(short4*)(xb + i) = o;
        return;
    }
    __shared__ float S[64][65];
    const float* in; short* out; int Kd, Nd, bx, by;
    if (bid < 2816) {
        int b = bid - 2048;              // (48, 16)
        bx = b % 48; by = b / 48;
        in = w_attn; out = wabT; Kd = C; Nd = N3;
    } else {
        int b = bid - 2816;              // (16, 16)
        bx = b % 16; by = b / 16;
        in = w_proj; out = wpbT; Kd = C; Nd = C;
    }
    int n0 = bx * 64, k0 = by * 64;
    #pragma unroll
    for (int i = 0; i < 16; ++i) {
        int lin = tid + i * 256;
        int r = lin >> 6, c = lin & 63;
        S[r][c] = in[(size_t)(k0 + r) * Nd + n0 + c];
    }
    __syncthreads();
    #pragma unroll
    for (int i = 0; i < 16; ++i) {
        int lin = tid + i * 256;
        int rn = lin >> 6, ck = lin & 63;
        out[(size_t)(n0 + rn) * Kd + k0 + ck] = f2bf(S[ck][rn]);
    }
}

// ---------------- bf16 GEMM (B^T): 64x128 tile, BK=32, 4 waves (2x2) ----------------
// EPI=0: plain out (+bias), f32/bf16 per OUT_BF16.
// EPI=1: fused QKV epilogue at LOW register pressure (acc[2][4]=32 VGPR):
//        q/k roped from direct __sincosf + d=63 fixups; v written only as
//        exp(cum)-scaled transpose into vbT. qkvb v-section never written.
template <int OUT_BF16, int EPI>
__global__ __launch_bounds__(256) void gemm_bt64(const short* __restrict__ A,
                                                 const short* __restrict__ Bt,
                                                 const float* __restrict__ bias,
                                                 void* __restrict__ Cout,
                                                 int M, int N, int K,
                                                 const float* __restrict__ partial,
                                                 const float* __restrict__ cumsc,
                                                 const float* __restrict__ pm_tok,
                                                 short* __restrict__ vbT) {
    __shared__ alignas(16) short As[64 * 32];
    __shared__ alignas(16) short Bs[128 * 32];
    int tid = threadIdx.x;
    int m0 = blockIdx.y * 64, n0 = blockIdx.x * 128;
    int w = tid >> 6, l = tid & 63;
    int wm = (w >> 1) * 32, wn = (w & 1) * 64;
    int lq = l & 15, g = l >> 4;
    int prow = l >> 2, pcol = (l & 3) * 8;    // lane slot within a 1KB chunk (16 rows x 32 cols)
    f32x4 acc[2][4] = {};
    for (int k0 = 0; k0 < K; k0 += 32) {
        {   // A: 4 chunks (1 per wave); B: 8 chunks (2 per wave)
            int rowA = w * 16 + prow;
            gload_lds16(A + (size_t)(m0 + rowA) * K + k0 + pcol, As + w * 512);
            #pragma unroll
            for (int i = 0; i < 2; ++i) {
                int c = w * 2 + i;
                int row = c * 16 + prow;
                gload_lds16(Bt + (size_t)(n0 + row) * K + k0 + pcol, Bs + c * 512);
            }
        }
        __syncthreads();
        bf16x8 af[2], bfr[4];
        #pragma unroll
        for (int f = 0; f < 2; ++f)
            af[f] = *(const bf16x8*)(As + (wm + f * 16 + lq) * 32 + g * 8);
        #pragma unroll
        for (int j = 0; j < 4; ++j)
            bfr[j] = *(const bf16x8*)(Bs + (wn + j * 16 + lq) * 32 + g * 8);
        #pragma unroll
        for (int fi = 0; fi < 2; ++fi)
            #pragma unroll
            for (int fj = 0; fj < 4; ++fj)
                acc[fi][fj] = MFMA16(af[fi], bfr[fj], acc[fi][fj]);
        __syncthreads();
    }

    if (EPI == 0) {
        #pragma unroll
        for (int fi = 0; fi < 2; ++fi)
            #pragma unroll
            for (int fj = 0; fj < 4; ++fj)
                #pragma unroll
                for (int r = 0; r < 4; ++r) {
                    int m = m0 + wm + fi * 16 + g * 4 + r;
                    int n = n0 + wn + fj * 16 + lq;
                    float v = acc[fi][fj][r] + bias[n];
                    if (OUT_BF16) ((short*)Cout)[(size_t)m * N + n] = f2bf(v);
                    else          ((float*)Cout)[(size_t)m * N + n] = v;
                }
    } else {
        // wave strip = one head (64 cols) at cb; 128-col tiles never straddle sections.
        short* Cb = (short*)Cout;              // qkvb
        int cb = n0 + wn;
        int section = cb >> 10;                // 0 q, 1 k, 2 v
        float b0 = bias[cb + lq],      b1 = bias[cb + 16 + lq];
        float b2 = bias[cb + 32 + lq], b3 = bias[cb + 48 + lq];
        if (section < 2) {
            bool isQ = (section == 0);
            float inv0 = exp2f(-(float)lq * (13.287712379549449f / 32.0f));         // j = lq
            float inv1 = exp2f(-(float)(lq + 16) * (13.287712379549449f / 32.0f));  // j = lq+16
            #pragma unroll
            for (int fi = 0; fi < 2; ++fi)
                #pragma unroll
                for (int r = 0; r < 4; ++r) {
                    int trow = m0 + wm + fi * 16 + g * 4 + r;
                    float pt = partial[trow];
                    float sn0, cs0, sn1, cs1;
                    __sincosf(pt * inv0, &sn0, &cs0);
                    __sincosf(pt * inv1, &sn1, &cs1);
                    float a0 = acc[fi][0][r] + b0;
                    float a1 = acc[fi][1][r] + b1;
                    float a2 = acc[fi][2][r] + b2;
                    float a3 = acc[fi][3][r] + b3;
                    float lo0 = a0 * cs0 - a2 * sn0;
                    float hi0 = a2 * cs0 + a0 * sn0;
                    float lo1 = a1 * cs1 - a3 * sn1;
                    float hi1 = a3 * cs1 + a1 * sn1;
                    if (lq == 15) {   // d == 63 fixups (padding folded in)
                        float pm = pm_tok[trow];
                        hi1 = isQ ? ((pm != 0.0f) ? 1.0f : 0.0f)
                                  : ((pm != 0.0f) ? cumsc[trow] : -1e20f);
                    }
                    size_t base = (size_t)trow * N3 + cb;
                    Cb[base + lq]      = f2bf(lo0);
                    Cb[base + 16 + lq] = f2bf(lo1);
                    Cb[base + 32 + lq] = f2bf(hi0);
                    Cb[base + 48 + lq] = f2bf(hi1);
                }
        } else {
            // V: write only transposed + exp(cum)-scaled vbT[h*64+d][t], 8B stores (4 consecutive t)
            int h = (cb - 2 * C) >> 6;
            #pragma unroll
            for (int fi = 0; fi < 2; ++fi) {
                int tb = m0 + wm + fi * 16 + g * 4;
                float ef[4];
                #pragma unroll
                for (int r = 0; r < 4; ++r) ef[r] = __expf(cumsc[tb + r]);
                #pragma unroll
                for (int fj = 0; fj < 4; ++fj) {
                    int d = fj * 16 + lq;
                    float bv = (fj == 0) ? b0 : (fj == 1) ? b1 : (fj == 2) ? b2 : b3;
                    short4 o;
                    o.x = f2bf((acc[fi][fj][0] + bv) * ef[0]);
                    o.y = f2bf((acc[fi][fj][1] + bv) * ef[1]);
                    o.z = f2bf((acc[fi][fj][2] + bv) * ef[2]);
                    o.w = f2bf((acc[fi][fj][3] + bv) * ef[3]);
                    *(short4*)(vbT + (size_t)(h * 64 + d) * T + tb) = o;
                }
            }
        }
    }
}

// ---------------- MFMA flash attention: staged dbuf + streaming softmax + paired balance ----------------
// 512 blocks. Pair (b, b+256) -> same XCD (256%8==0): work sums to 33 tiles.
__global__ __launch_bounds__(256) void attn_flash(const short* __restrict__ qkvb,
                                                  const short* __restrict__ vbT,
                                                  short* __restrict__ yb) {
    __shared__ alignas(16) short Kt[2][64 * 64];      // [k][d], XOR-swizzled rows
    __shared__ alignas(16) short Vt[2][64 * 64];      // [d][k], XOR-swizzled rows
    __shared__ alignas(16) short Ps[4][16][72];       // wave-private P[q][k]

    int b = blockIdx.x;
    int h, qt;
    if (b < 256) { h = b & 15; qt = 31 - (b >> 4); }          // long half: qt 16..31
    else         { int c2 = b - 256; h = c2 & 15; qt = c2 >> 4; }  // short half: qt 0..15
    int tid = threadIdx.x;
    int w = tid >> 6, l = tid & 63;
    int lq = l & 15, g = l >> 4;
    int qrl = w * 16 + lq;                             // q-row local to the 64-row q-tile

    const short* qbase = qkvb + (size_t)(qt * 64 + qrl) * N3 + h * 64;
    bf16x8 qf0 = *(const bf16x8*)(qbase + g * 8);
    bf16x8 qf1 = *(const bf16x8*)(qbase + 32 + g * 8);

    f32x4 accO[4] = {};    // [f]: d = 16f + lq ; q-rows = 4g + r
    float lsum = 0.0f;

    // staging geometry: thread covers rows srow, srow+32; 8 cols at scol
    int srow = tid >> 3, scol = (tid & 7) * 8;
    const short* kgb = qkvb + C + h * 64 + scol;
    const short* vgb = vbT + (size_t)(h * 64) * T + scol;
    int wb0 = srow * 128 + ((scol * 2) ^ ((srow & 7) << 4));
    int wb1 = (srow + 32) * 128 + ((scol * 2) ^ ((srow & 7) << 4));

    auto do_tile = [&](int cur, bool masked) {
        const char* Kc = (const char*)Kt[cur];
        const char* Vc = (const char*)Vt[cur];
        // ---- S^T = K · Q^T ----
        f32x4 s[4] = {};
        __builtin_amdgcn_s_setprio(1);
        #pragma unroll
        for (int f = 0; f < 4; ++f) {
            int row = f * 16 + lq;
            const char* kr_ = Kc + row * 128;
            int sw = (row & 7) << 4;
            bf16x8 a0 = *(const bf16x8*)(kr_ + ((g * 16) ^ sw));
            bf16x8 a1 = *(const bf16x8*)(kr_ + ((64 + g * 16) ^ sw));
            s[f] = MFMA16(a0, qf0, s[f]);
            s[f] = MFMA16(a1, qf1, s[f]);
        }
        __builtin_amdgcn_s_setprio(0);
        // ---- streaming softmax: p = exp(s/8), no max-tracking ----
        float p[16];
        #pragma unroll
        for (int f = 0; f < 4; ++f)
            #pragma unroll
            for (int r = 0; r < 4; ++r) {
                float sv = s[f][r] * 0.125f;
                if (masked) {
                    int kl = f * 16 + g * 4 + r;
                    sv = (kl > qrl) ? -INFINITY : sv;
                }
                float pv = __expf(sv);
                p[f * 4 + r] = pv;
                lsum += pv;
            }
        // ---- pack P to bf16, transpose through wave-private LDS ----
        #pragma unroll
        for (int f = 0; f < 4; ++f) {
            unsigned u0, u1;
            asm("v_cvt_pk_bf16_f32 %0, %1, %2" : "=v"(u0) : "v"(p[f * 4 + 0]), "v"(p[f * 4 + 1]));
            asm("v_cvt_pk_bf16_f32 %0, %1, %2" : "=v"(u1) : "v"(p[f * 4 + 2]), "v"(p[f * 4 + 3]));
            uint2 uu; uu.x = u0; uu.y = u1;
            *(uint2*)&Ps[w][lq][f * 16 + g * 4] = uu;
        }
        // ---- O += P · V ----
        __builtin_amdgcn_s_setprio(1);
        #pragma unroll
        for (int kh = 0; kh < 2; ++kh) {
            bf16x8 pa = *(const bf16x8*)&Ps[w][lq][kh * 32 + g * 8];
            #pragma unroll
            for (int f = 0; f < 4; ++f) {
                int vrow = f * 16 + lq;
                const char* vr_ = Vc + vrow * 128;
                bf16x8 vb = *(const bf16x8*)(vr_ + (((kh * 32 + g * 8) * 2) ^ ((vrow & 7) << 4)));
                accO[f] = MFMA16(pa, vb, accO[f]);
            }
        }
        __builtin_amdgcn_s_setprio(0);
    };

    // prologue: stage tile 0
    uint4 kr0 = *(const uint4*)(kgb + (size_t)srow * N3);
    uint4 kr1 = *(const uint4*)(kgb + (size_t)(srow + 32) * N3);
    uint4 vr0 = *(const uint4*)(vgb + (size_t)srow * T);
    uint4 vr1 = *(const uint4*)(vgb + (size_t)(srow + 32) * T);
    *(uint4*)((char*)Kt[0] + wb0) = kr0;
    *(uint4*)((char*)Kt[0] + wb1) = kr1;
    *(uint4*)((char*)Vt[0] + wb0) = vr0;
    *(uint4*)((char*)Vt[0] + wb1) = vr1;
    __syncthreads();

    for (int t = 0; t < qt; ++t) {
        int kn = (t + 1) * 64;
        kr0 = *(const uint4*)(kgb + (size_t)(kn + srow) * N3);
        kr1 = *(const uint4*)(kgb + (size_t)(kn + srow + 32) * N3);
        vr0 = *(const uint4*)(vgb + (size_t)srow * T + kn);
        vr1 = *(const uint4*)(vgb + (size_t)(srow + 32) * T + kn);

        do_tile(t & 1, false);

        int nxt = (t & 1) ^ 1;
        *(uint4*)((char*)Kt[nxt] + wb0) = kr0;
        *(uint4*)((char*)Kt[nxt] + wb1) = kr1;
        *(uint4*)((char*)Vt[nxt] + wb0) = vr0;
        *(uint4*)((char*)Vt[nxt] + wb1) = vr1;
        __syncthreads();
    }
    do_tile(qt & 1, true);   // diagonal tile, causal mask

    // final l reduction over the 4 g-groups
    lsum += __shfl_xor(lsum, 16);
    lsum += __shfl_xor(lsum, 32);
    float linv_own = 1.0f / lsum;
    float li[4];
    #pragma unroll
    for (int r = 0; r < 4; ++r) li[r] = __shfl(linv_own, g * 4 + r);

    #pragma unroll
    for (int f = 0; f < 4; ++f)
        #pragma unroll
        for (int r = 0; r < 4; ++r) {
            int trow = qt * 64 + w * 16 + g * 4 + r;
            yb[(size_t)trow * C + h * 64 + f * 16 + lq] = f2bf(accO[f][r] * li[r]);
        }
}

extern "C" void kernel_launch(void* const* d_in, const int* in_sizes, int n_in,
                              void* d_out, int out_size, void* d_ws, size_t ws_size,
                              hipStream_t stream) {
    const float* x       = (const float*)d_in[0];
    const float* cumsc   = (const float*)d_in[1];
    const float* padmask = (const float*)d_in[2];
    const int*   tok     = (const int*)d_in[3];
    const float* w_attn  = (const float*)d_in[4];
    const float* b_attn  = (const float*)d_in[5];
    const float* w_proj  = (const float*)d_in[6];
    const float* b_proj  = (const float*)d_in[7];
    float* out = (float*)d_out;

    float* part   = (float*)d_ws;                 // 2048
    float* pm_tok = part + 2048;                  // 2048
    short* xb     = (short*)(pm_tok + 2048);      // T*C
    short* wabT   = xb + (size_t)T * C;           // 3C*C
    short* wpbT   = wabT + (size_t)N3 * C;        // C*C
    short* qkvb   = wpbT + (size_t)C * C;         // T*3C (v-section unused)
    short* vbT    = qkvb + (size_t)T * N3;        // C*T
    short* yb     = vbT + (size_t)C * T;          // T*C

    pre_kernel<<<3073, 256, 0, stream>>>(x, w_attn, w_proj, tok, padmask,
                                         xb, wabT, wpbT, part, pm_tok);
    gemm_bt64<1, 1><<<dim3(N3 / 128, T / 64), 256, 0, stream>>>(
        xb, wabT, b_attn, qkvb, T, N3, C, part, cumsc, pm_tok, vbT);
    attn_flash<<<512, 256, 0, stream>>>(qkvb, vbT, yb);
    gemm_bt64<0, 0><<<dim3(C / 128, T / 64), 256, 0, stream>>>(
        yb, wpbT, b_proj, out, T, C, C, nullptr, nullptr, nullptr, nullptr);
}